// Round 6
// baseline (791.345 us; speedup 1.0000x reference)
//
#include <hip/hip_runtime.h>
#include <hip/hip_bf16.h>

#define NN 500000
#define EE 2000000
#define GG 16384
#define ND 44
#define ED 12
#define HH 64
#define EMB 128
#define NBLK 123          // ceil(NN / 4096) scan blocks
#define NTILE (NN / 16)   // 31250, exact

typedef __attribute__((ext_vector_type(8))) short bf16x8;
typedef __attribute__((ext_vector_type(4))) float f32x4;
typedef __attribute__((ext_vector_type(2))) _Float16 h2v;

// fp32 -> bf16 round-to-nearest-even, bit pattern as short
__device__ inline short f2bf(float v) {
    unsigned int x = __builtin_bit_cast(unsigned int, v);
    x += 0x7FFFu + ((x >> 16) & 1u);
    return (short)(x >> 16);
}
// fp32 <-> fp16 (RNE)
__device__ inline unsigned short f2h(float v) {
    return __builtin_bit_cast(unsigned short, (_Float16)v);
}
__device__ inline float h2f(unsigned short s) {
    return (float)__builtin_bit_cast(_Float16, s);
}
__device__ inline unsigned pkh(float a, float b) {
    return (unsigned)f2h(a) | ((unsigned)f2h(b) << 16);
}
__device__ inline float2 upk(unsigned u) {
    return make_float2((float)__builtin_bit_cast(_Float16, (unsigned short)(u & 0xffffu)),
                       (float)__builtin_bit_cast(_Float16, (unsigned short)(u >> 16)));
}
// f32 += dot(half2, half2) — single v_dot2_f32_f16 where available
__device__ inline float hdot2(unsigned a, unsigned b, float c) {
#if __has_builtin(__builtin_amdgcn_fdot2)
    return __builtin_amdgcn_fdot2(__builtin_bit_cast(h2v, a),
                                  __builtin_bit_cast(h2v, b), c, false);
#else
    float2 av = upk(a), bv = upk(b);
    return fmaf(av.y, bv.y, fmaf(av.x, bv.x, c));
#endif
}

// Wave-local LDS ordering fence (per-wave LDS buffers; does NOT drain vmcnt).
__device__ inline void wave_lds_fence() {
    asm volatile("s_waitcnt lgkmcnt(0)" ::: "memory");
    __builtin_amdgcn_sched_barrier(0);
}

// ---------------------------------------------------------------------------
// Weight prep: transpose to [n][k] layout, cast to bf16, zero-pad K of w1a to 64
__global__ __launch_bounds__(256) void prep_weights(
    const float* __restrict__ w1a, const float* __restrict__ w1b,
    const float* __restrict__ w2a, const float* __restrict__ w2b,
    short* __restrict__ o) {
    int t = blockIdx.x * 256 + threadIdx.x;
    if (t < 4096) {
        int n = t >> 6, k = t & 63;
        o[t] = f2bf(k < ND ? w1a[k * HH + n] : 0.f);
    } else if (t < 8192) {
        int u = t - 4096; int n = u >> 6, k = u & 63;
        o[t] = f2bf(w1b[k * HH + n]);
    } else if (t < 16384) {
        int u = t - 8192; int n = u >> 6, k = u & 63;
        o[t] = f2bf(w2a[k * EMB + n]);
    } else if (t < 32768) {
        int u = t - 16384; int n = u >> 7, k = u & 127;
        o[t] = f2bf(w2b[k * EMB + n]);
    }
}

// x [N][44] f32 -> xh [N][64] fp16, zero-padded, 128B-aligned rows.
// Gather rows then span exactly 2 cache lines instead of 3-4.
__global__ __launch_bounds__(256) void x_to_h(const float* __restrict__ x,
                                             unsigned short* __restrict__ xh) {
    for (long long t = (long long)(blockIdx.x) * 256 + threadIdx.x;
         t < (long long)NN * 64; t += (long long)gridDim.x * 256) {
        int i = (int)(t >> 6), c = (int)(t & 63);
        xh[t] = (c < ND) ? f2h(x[(size_t)i * ND + c]) : (unsigned short)0;
    }
}

// ---------------------------------------------------------------------------
// CSR build: histogram of dst, exclusive scan, scatter by dst.
__global__ __launch_bounds__(256) void hist_kernel(const int* __restrict__ ei,
                                                   int* __restrict__ deg) {
    int e = blockIdx.x * 256 + threadIdx.x;
    if (e < EE) atomicAdd(&deg[ei[EE + e]], 1);
}

__global__ __launch_bounds__(256) void scan_reduce(const int* __restrict__ deg,
                                                   int* __restrict__ bsum) {
    int b = blockIdx.x, t = threadIdx.x;
    int base = b * 4096;
    int s = 0;
    for (int i = t; i < 4096; i += 256) {
        int g = base + i;
        if (g < NN) s += deg[g];
    }
#pragma unroll
    for (int off = 32; off; off >>= 1) s += __shfl_xor(s, off);
    __shared__ int ws[4];
    if ((t & 63) == 0) ws[t >> 6] = s;
    __syncthreads();
    if (t == 0) bsum[b] = ws[0] + ws[1] + ws[2] + ws[3];
}

__global__ __launch_bounds__(128) void scan_mid(const int* __restrict__ bsum,
                                                int* __restrict__ boff,
                                                int* __restrict__ rowptr) {
    int t = threadIdx.x;
    int v = (t < NBLK) ? bsum[t] : 0;
    int x = v;
#pragma unroll
    for (int off = 1; off < 64; off <<= 1) {
        int y = __shfl_up(x, off);
        if ((t & 63) >= off) x += y;
    }
    __shared__ int wt[2];
    if ((t & 63) == 63) wt[t >> 6] = x;
    __syncthreads();
    int xx = x + ((t >= 64) ? wt[0] : 0);
    if (t < NBLK) boff[t] = xx - v;
    if (t == 127) rowptr[NN] = xx;
}

__global__ __launch_bounds__(256) void scan_final(const int* __restrict__ deg,
                                                  const int* __restrict__ boff,
                                                  int* __restrict__ rowptr,
                                                  int* __restrict__ cursor) {
    int b = blockIdx.x, t = threadIdx.x;
    int base = b * 4096 + t * 16;
    int loc[16];
    int s = 0;
#pragma unroll
    for (int j = 0; j < 16; ++j) {
        int g = base + j;
        loc[j] = (g < NN) ? deg[g] : 0;
        s += loc[j];
    }
    int xinc = s;
#pragma unroll
    for (int off = 1; off < 64; off <<= 1) {
        int y = __shfl_up(xinc, off);
        if ((t & 63) >= off) xinc += y;
    }
    __shared__ int wt[4];
    if ((t & 63) == 63) wt[t >> 6] = xinc;
    __syncthreads();
    int wv = t >> 6, woff = 0;
#pragma unroll
    for (int k = 0; k < 4; ++k)
        if (k < wv) woff += wt[k];
    int run = boff[b] + woff + (xinc - s);
#pragma unroll
    for (int j = 0; j < 16; ++j) {
        int g = base + j;
        if (g < NN) { rowptr[g] = run; cursor[g] = run; }
        run += loc[j];
    }
}

// Scatter: build 32B CSR rows: [12 x fp16 edge-attr (24B) | src int (4B) | pad].
__global__ __launch_bounds__(256) void scatter_kernel(const int* __restrict__ ei,
                                                      const float* __restrict__ ea,
                                                      int* __restrict__ cursor,
                                                      unsigned int* __restrict__ csr) {
    int e = blockIdx.x * 256 + threadIdx.x;
    if (e < EE) {
        int dst = ei[EE + e];
        const float4* s = (const float4*)(ea + (size_t)e * ED);
        float4 a0 = s[0], a1 = s[1], a2 = s[2];
        uint4 P0, P1;
        P0.x = pkh(a0.x, a0.y); P0.y = pkh(a0.z, a0.w);
        P0.z = pkh(a1.x, a1.y); P0.w = pkh(a1.z, a1.w);
        P1.x = pkh(a2.x, a2.y); P1.y = pkh(a2.z, a2.w);
        P1.z = (unsigned)ei[e];   // src at word 6
        P1.w = 0u;
        int pos = atomicAdd(&cursor[dst], 1);
        uint4* d = (uint4*)(csr + (size_t)pos * 8);
        d[0] = P0; d[1] = P1;
    }
}

// ---------------------------------------------------------------------------
// Gather aggregation, 8 nodes/wave, fused skip-add + bf16 output:
//   out16[i][0:64] = bf16( xf[i] + sum_{e: dst=i} relu(xf[src] + ea@W + b) )
// Source rows are fp16 [N][64] for BOTH layers (layer1: pre-converted x).
// Per-edge math: 6 x v_dot2_f32_f16 on packed fp16 attr/weight pairs.
// 8-deep forced pipeline (sched_barrier after each LOADE pair).
template <int D>
__global__ __launch_bounds__(256) void agg_gather(
    const unsigned short* __restrict__ xh,
    const unsigned int* __restrict__ cea,
    const float* __restrict__ ew, const float* __restrict__ eb,
    const int* __restrict__ rowptr,
    short* __restrict__ out) {
    int lane = threadIdx.x & 63;
    int wv = threadIdx.x >> 6;
    int i0 = (blockIdx.x * 4 + wv) * 8;
    if (i0 >= NN) return;
    // weights packed as 6 fp16 pairs per lane (lanes >= D get zeros)
    unsigned wp0, wp1, wp2, wp3, wp4, wp5;
    float breg;
    if (D == 64 || lane < D) {
        wp0 = pkh(ew[0 * D + lane], ew[1 * D + lane]);
        wp1 = pkh(ew[2 * D + lane], ew[3 * D + lane]);
        wp2 = pkh(ew[4 * D + lane], ew[5 * D + lane]);
        wp3 = pkh(ew[6 * D + lane], ew[7 * D + lane]);
        wp4 = pkh(ew[8 * D + lane], ew[9 * D + lane]);
        wp5 = pkh(ew[10 * D + lane], ew[11 * D + lane]);
        breg = eb[lane];
    } else {
        wp0 = wp1 = wp2 = wp3 = wp4 = wp5 = 0u; breg = 0.f;
    }
    int rp = (lane <= 8) ? rowptr[i0 + lane] : 0;
    int beg = __builtin_amdgcn_readfirstlane(__builtin_amdgcn_readlane(rp, 0));
    int end = __builtin_amdgcn_readfirstlane(__builtin_amdgcn_readlane(rp, 8));
    int s0 = 0, s1 = 0;
    if (beg + lane < end) s0 = (int)cea[(size_t)(beg + lane) * 8 + 6];
    if (beg + 64 + lane < end) s1 = (int)cea[(size_t)(beg + 64 + lane) * 8 + 6];

    auto SKIPLD = [&](int j) -> float {
        return h2f(xh[(size_t)(i0 + j) * 64 + lane]);
    };

    float acc = 0.f;
    int np = 0;
    int nb = __builtin_amdgcn_readlane(rp, 1);
    float sk = SKIPLD(0);
    while (np < 8 && nb == beg) {
        out[(size_t)(i0 + np) * 64 + lane] = f2bf(sk);   // acc == 0
        ++np;
        nb = (np < 8) ? __builtin_amdgcn_readlane(rp, np + 1) : 0x7fffffff;
        sk = (np < 8) ? SKIPLD(np) : 0.f;
    }

    // Unconditional load with clamp (valid because beg < end when called).
    auto LOADE = [&](int pos, uint4& P0, uint2& P1, unsigned short& XR) {
        int p = pos < end ? pos : end - 1;
        int off = p - beg;
        int src;
        if (off < 64)       src = __builtin_amdgcn_readlane(s0, off);
        else if (off < 128) src = __builtin_amdgcn_readlane(s1, off - 64);
        else                src = __builtin_amdgcn_readfirstlane((int)cea[(size_t)p * 8 + 6]);
        P0 = *(const uint4*)(cea + (size_t)p * 8);
        P1 = *(const uint2*)(cea + (size_t)p * 8 + 4);
        XR = xh[(size_t)src * 64 + lane];
    };
    auto CONSUME = [&](int pos, const uint4& P0, const uint2& P1, unsigned short XR) {
        if (pos < end) {
            float elin = breg;
            elin = hdot2(P0.x, wp0, elin);
            elin = hdot2(P0.y, wp1, elin);
            elin = hdot2(P0.z, wp2, elin);
            elin = hdot2(P0.w, wp3, elin);
            elin = hdot2(P1.x, wp4, elin);
            elin = hdot2(P1.y, wp5, elin);
            acc += fmaxf(h2f(XR) + elin, 0.f);
            int p1 = pos + 1;
            if (p1 == nb) {
                do {
                    out[(size_t)(i0 + np) * 64 + lane] = f2bf(acc + sk);
                    acc = 0.f; ++np;
                    nb = (np < 8) ? __builtin_amdgcn_readlane(rp, np + 1) : 0x7fffffff;
                    sk = (np < 8) ? SKIPLD(np) : 0.f;
                } while (p1 == nb);
            }
        }
    };

    if (beg >= end) return;   // all 8 nodes empty (already flushed above)

    uint4 A0, B0, C0, D0, E0, F0, G0, H0;
    uint2 A1, B1, C1, D1, E1, F1, G1, H1;
    unsigned short Ax, Bx, Cx, Dx, Ex, Fx, Gx, Hx;
    int base = beg;
    LOADE(base + 0, A0, A1, Ax);
    LOADE(base + 1, B0, B1, Bx);
    LOADE(base + 2, C0, C1, Cx);
    LOADE(base + 3, D0, D1, Dx);
    LOADE(base + 4, E0, E1, Ex);
    LOADE(base + 5, F0, F1, Fx);
    LOADE(base + 6, G0, G1, Gx);
    LOADE(base + 7, H0, H1, Hx);
    __builtin_amdgcn_sched_barrier(0);
    while (base < end) {
        CONSUME(base + 0, A0, A1, Ax);
        CONSUME(base + 1, B0, B1, Bx);
        LOADE(base + 8, A0, A1, Ax);
        LOADE(base + 9, B0, B1, Bx);
        __builtin_amdgcn_sched_barrier(0);
        if (base + 2 >= end) break;
        CONSUME(base + 2, C0, C1, Cx);
        CONSUME(base + 3, D0, D1, Dx);
        LOADE(base + 10, C0, C1, Cx);
        LOADE(base + 11, D0, D1, Dx);
        __builtin_amdgcn_sched_barrier(0);
        if (base + 4 >= end) break;
        CONSUME(base + 4, E0, E1, Ex);
        CONSUME(base + 5, F0, F1, Fx);
        LOADE(base + 12, E0, E1, Ex);
        LOADE(base + 13, F0, F1, Fx);
        __builtin_amdgcn_sched_barrier(0);
        if (base + 6 >= end) break;
        CONSUME(base + 6, G0, G1, Gx);
        CONSUME(base + 7, H0, H1, Hx);
        LOADE(base + 14, G0, G1, Gx);
        LOADE(base + 15, H0, H1, Hx);
        __builtin_amdgcn_sched_barrier(0);
        base += 8;
    }
}

// ---------------------------------------------------------------------------
// Node MLP 1: h = relu( relu(a @ w1a + b1a) @ w1b + b1b ), a = bf16[N][64] in.
// Persistent waves, register-resident weights (64 VGPR total), per-wave LDS.
#define HSTR1 68
__global__ __launch_bounds__(256, 3) void mlp1(
    const short* __restrict__ ain,
    const short* __restrict__ w1a_t, const float* __restrict__ b1a,
    const short* __restrict__ w1b_t, const float* __restrict__ b1b,
    unsigned short* __restrict__ h) {
    __shared__ float hid[4][16 * HSTR1];
    int lane = threadIdx.x & 63;
    int wv = threadIdx.x >> 6;
    int mrow = lane & 15, q = lane >> 4;
    float* hw = hid[wv];

    bf16x8 wa[4][2], wb[4][2];
    float ba[4], bb[4];
#pragma unroll
    for (int nt = 0; nt < 4; ++nt) {
        int n = nt * 16 + mrow;
        ba[nt] = b1a[n]; bb[nt] = b1b[n];
#pragma unroll
        for (int s = 0; s < 2; ++s) {
            wa[nt][s] = *(const bf16x8*)(w1a_t + n * 64 + s * 32 + q * 8);
            wb[nt][s] = *(const bf16x8*)(w1b_t + n * 64 + s * 32 + q * 8);
        }
    }

    int tile = blockIdx.x * 4 + wv;
    int stride = gridDim.x * 4;
    if (tile >= NTILE) return;
    bf16x8 a0 = *(const bf16x8*)(ain + (size_t)(tile * 16 + mrow) * 64 + q * 8);
    bf16x8 a1 = *(const bf16x8*)(ain + (size_t)(tile * 16 + mrow) * 64 + 32 + q * 8);
    while (true) {
        int nxt = tile + stride;
        bool more = nxt < NTILE;
        bf16x8 na0{}, na1{};
        if (more) {
            na0 = *(const bf16x8*)(ain + (size_t)(nxt * 16 + mrow) * 64 + q * 8);
            na1 = *(const bf16x8*)(ain + (size_t)(nxt * 16 + mrow) * 64 + 32 + q * 8);
        }
        int node0 = tile * 16;
#pragma unroll
        for (int nt = 0; nt < 4; ++nt) {
            f32x4 acc = {ba[nt], ba[nt], ba[nt], ba[nt]};
            acc = __builtin_amdgcn_mfma_f32_16x16x32_bf16(a0, wa[nt][0], acc, 0, 0, 0);
            acc = __builtin_amdgcn_mfma_f32_16x16x32_bf16(a1, wa[nt][1], acc, 0, 0, 0);
            int n = nt * 16 + mrow;
#pragma unroll
            for (int r = 0; r < 4; ++r)
                hw[(q * 4 + r) * HSTR1 + n] = fmaxf(acc[r], 0.f);
        }
        wave_lds_fence();
        bf16x8 af2[2];
#pragma unroll
        for (int s = 0; s < 2; ++s) {
            f32x4 v0 = *(const f32x4*)(hw + mrow * HSTR1 + s * 32 + q * 8);
            f32x4 v1 = *(const f32x4*)(hw + mrow * HSTR1 + s * 32 + q * 8 + 4);
#pragma unroll
            for (int j = 0; j < 4; ++j) { af2[s][j] = f2bf(v0[j]); af2[s][j + 4] = f2bf(v1[j]); }
        }
#pragma unroll
        for (int nt = 0; nt < 4; ++nt) {
            f32x4 acc = {bb[nt], bb[nt], bb[nt], bb[nt]};
            acc = __builtin_amdgcn_mfma_f32_16x16x32_bf16(af2[0], wb[nt][0], acc, 0, 0, 0);
            acc = __builtin_amdgcn_mfma_f32_16x16x32_bf16(af2[1], wb[nt][1], acc, 0, 0, 0);
            int n = nt * 16 + mrow;
#pragma unroll
            for (int r = 0; r < 4; ++r)
                h[(size_t)(node0 + q * 4 + r) * HH + n] = f2h(fmaxf(acc[r], 0.f));
        }
        if (!more) break;
        tile = nxt; a0 = na0; a1 = na1;
        wave_lds_fence();   // order this iter's hw reads vs next iter's writes
    }
}

// ---------------------------------------------------------------------------
// Node MLP 2 + fused mean-pool accumulate: input = bf16[N][64] (h+agg2 fused).
// Persistent waves (grid 512 = 2 blocks/CU). wa register-resident; w2b staged
// once per block into LDS (stride 136 shorts -> ~2-way bank alias, free).
#define HSTR2 132
#define WLSTR 136
__global__ __launch_bounds__(256, 2) void mlp2(
    const short* __restrict__ ain,
    const short* __restrict__ w2a_t, const float* __restrict__ b2a,
    const short* __restrict__ w2b_t, const float* __restrict__ b2b,
    const int* __restrict__ batch, float* __restrict__ sums) {
    __shared__ float buf[4][16 * HSTR2];
    __shared__ short wlds[EMB * WLSTR];
    int lane = threadIdx.x & 63;
    int wv = threadIdx.x >> 6;
    int mrow = lane & 15, q = lane >> 4;
    float* bw = buf[wv];

    // stage w2b -> LDS once per block (16384 shorts)
    for (int idx = threadIdx.x * 8; idx < EMB * EMB; idx += 2048) {
        int n = idx >> 7, k = idx & 127;
        *(bf16x8*)(wlds + n * WLSTR + k) = *(const bf16x8*)(w2b_t + idx);
    }

    bf16x8 wa[8][2];
    float ba[8], bb[8];
#pragma unroll
    for (int nt = 0; nt < 8; ++nt) {
        int n = nt * 16 + mrow;
        ba[nt] = b2a[n]; bb[nt] = b2b[n];
#pragma unroll
        for (int s = 0; s < 2; ++s)
            wa[nt][s] = *(const bf16x8*)(w2a_t + n * HH + s * 32 + q * 8);
    }
    __syncthreads();   // once: wlds visible to all waves

    int tile = blockIdx.x * 4 + wv;
    int stride = gridDim.x * 4;
    if (tile >= NTILE) return;
    bf16x8 a0 = *(const bf16x8*)(ain + (size_t)(tile * 16 + mrow) * 64 + q * 8);
    bf16x8 a1 = *(const bf16x8*)(ain + (size_t)(tile * 16 + mrow) * 64 + 32 + q * 8);
    int bv = (lane < 16) ? batch[tile * 16 + lane] : 0;
    while (true) {
        int nxt = tile + stride;
        bool more = nxt < NTILE;
        bf16x8 na0{}, na1{};
        int nbv = 0;
        if (more) {
            na0 = *(const bf16x8*)(ain + (size_t)(nxt * 16 + mrow) * 64 + q * 8);
            na1 = *(const bf16x8*)(ain + (size_t)(nxt * 16 + mrow) * 64 + 32 + q * 8);
            nbv = (lane < 16) ? batch[nxt * 16 + lane] : 0;
        }
        // GEMM1: 64 -> 128, relu, to LDS (transpose staging)
#pragma unroll
        for (int nt = 0; nt < 8; ++nt) {
            f32x4 acc = {ba[nt], ba[nt], ba[nt], ba[nt]};
            acc = __builtin_amdgcn_mfma_f32_16x16x32_bf16(a0, wa[nt][0], acc, 0, 0, 0);
            acc = __builtin_amdgcn_mfma_f32_16x16x32_bf16(a1, wa[nt][1], acc, 0, 0, 0);
            int n = nt * 16 + mrow;
#pragma unroll
            for (int r = 0; r < 4; ++r)
                bw[(q * 4 + r) * HSTR2 + n] = fmaxf(acc[r], 0.f);
        }
        wave_lds_fence();
        bf16x8 af2[4];
#pragma unroll
        for (int s = 0; s < 4; ++s) {
            f32x4 v0 = *(const f32x4*)(bw + mrow * HSTR2 + s * 32 + q * 8);
            f32x4 v1 = *(const f32x4*)(bw + mrow * HSTR2 + s * 32 + q * 8 + 4);
#pragma unroll
            for (int j = 0; j < 4; ++j) { af2[s][j] = f2bf(v0[j]); af2[s][j + 4] = f2bf(v1[j]); }
        }
        // GEMM2: 128 -> 128, B-fragments streamed from LDS, raw acc to LDS
#pragma unroll
        for (int nt = 0; nt < 8; ++nt) {
            f32x4 acc = {bb[nt], bb[nt], bb[nt], bb[nt]};
#pragma unroll
            for (int s = 0; s < 4; ++s) {
                bf16x8 bfrag = *(const bf16x8*)(wlds + (nt * 16 + mrow) * WLSTR + s * 32 + q * 8);
                acc = __builtin_amdgcn_mfma_f32_16x16x32_bf16(af2[s], bfrag, acc, 0, 0, 0);
            }
#pragma unroll
            for (int r = 0; r < 4; ++r)
                bw[(q * 4 + r) * HSTR2 + nt * 16 + mrow] = acc[r];
        }
        wave_lds_fence();
        // fused mean-pool accumulate (batch sorted -> few runs per tile)
#pragma unroll
        for (int cp = 0; cp < 2; ++cp) {
            int col = lane + cp * 64;
            float run = 0.f;
            int bprev = __shfl(bv, 0);
            for (int i = 0; i < 16; ++i) {
                int bg = __shfl(bv, i);
                if (bg != bprev) {
                    atomicAdd(&sums[bprev * EMB + col], run);
                    run = 0.f; bprev = bg;
                }
                run += bw[i * HSTR2 + col];
            }
            atomicAdd(&sums[bprev * EMB + col], run);
        }
        if (!more) break;
        tile = nxt; a0 = na0; a1 = na1; bv = nbv;
        wave_lds_fence();   // order pooling reads vs next iter's GEMM1 writes
    }
}

// ---------------------------------------------------------------------------
__global__ __launch_bounds__(128) void finalize(
    const float* __restrict__ sums, const int* __restrict__ batch,
    float* __restrict__ out) {
    int g = blockIdx.x;
    __shared__ int cnt_s;
    if (threadIdx.x == 0) {
        int lo = 0, hi = NN;
        while (lo < hi) { int mid = (lo + hi) >> 1; if (batch[mid] < g) lo = mid + 1; else hi = mid; }
        int lo2 = lo, hi2 = NN;
        while (lo2 < hi2) { int mid = (lo2 + hi2) >> 1; if (batch[mid] < g + 1) lo2 = mid + 1; else hi2 = mid; }
        cnt_s = lo2 - lo;
    }
    __syncthreads();
    int c = cnt_s > 1 ? cnt_s : 1;
    out[g * EMB + threadIdx.x] = sums[g * EMB + threadIdx.x] / (float)c;
}

// ---------------------------------------------------------------------------
extern "C" void kernel_launch(void* const* d_in, const int* in_sizes, int n_in,
                              void* d_out, int out_size, void* d_ws, size_t ws_size,
                              hipStream_t stream) {
    const float* x    = (const float*)d_in[0];
    const float* ea   = (const float*)d_in[1];
    const int*   ei   = (const int*)d_in[2];
    const int*   batch= (const int*)d_in[3];
    const float* el1w = (const float*)d_in[4];
    const float* el1b = (const float*)d_in[5];
    const float* w1a  = (const float*)d_in[6];
    const float* b1a  = (const float*)d_in[7];
    const float* w1b  = (const float*)d_in[8];
    const float* b1b  = (const float*)d_in[9];
    const float* el2w = (const float*)d_in[10];
    const float* el2b = (const float*)d_in[11];
    const float* w2a  = (const float*)d_in[12];
    const float* b2a  = (const float*)d_in[13];
    const float* w2b  = (const float*)d_in[14];
    const float* b2b  = (const float*)d_in[15];

    char* ws = (char*)d_ws;
    short*          aggout = (short*)ws;                    // [N][64] bf16 (64,000,000 B), both layers
    unsigned short* hbuf16 = (unsigned short*)(ws + 64000000); // [N][64] fp16 (64,000,000 B)
    unsigned int*   csr32  = (unsigned int*)(ws + 128000000);  // [E] 32B rows (64,000,000 B)
    int*   rowptr = (int*)(ws + 192000000);                 // N+1
    int*   cursor = (int*)(ws + 194000064);                 // N
    int*   deg    = (int*)(ws + 196000064);                 // N
    int*   bsum   = (int*)(ws + 198000064);                 // NBLK
    int*   boff   = (int*)(ws + 198000576);                 // NBLK
    float* sums   = (float*)(ws + 198001088);               // G*128 f32
    short* wts    = (short*)(ws + 206389696);               // 32768 shorts
    unsigned short* xh = (unsigned short*)(ws + 208000000); // [N][64] fp16 (64,000,000 B)
    short* w1a_t = wts;
    short* w1b_t = wts + 4096;
    short* w2a_t = wts + 8192;
    short* w2b_t = wts + 16384;

    hipMemsetAsync(deg, 0, (size_t)NN * 4, stream);
    hipMemsetAsync(sums, 0, (size_t)GG * EMB * 4, stream);

    prep_weights<<<128, 256, 0, stream>>>(w1a, w1b, w2a, w2b, wts);
    x_to_h<<<4096, 256, 0, stream>>>(x, xh);
    // CSR build (+ fp16 attr pack + src fused into 32B rows)
    hist_kernel<<<(EE + 255) / 256, 256, 0, stream>>>(ei, deg);
    scan_reduce<<<NBLK, 256, 0, stream>>>(deg, bsum);
    scan_mid<<<1, 128, 0, stream>>>(bsum, boff, rowptr);
    scan_final<<<NBLK, 256, 0, stream>>>(deg, boff, rowptr, cursor);
    scatter_kernel<<<(EE + 255) / 256, 256, 0, stream>>>(ei, ea, cursor, csr32);
    // Layer 1
    agg_gather<ND><<<NN / 32, 256, 0, stream>>>(xh, csr32, el1w, el1b, rowptr, aggout);
    mlp1<<<1024, 256, 0, stream>>>(aggout, w1a_t, b1a, w1b_t, b1b, hbuf16);
    // Layer 2
    agg_gather<HH><<<NN / 32, 256, 0, stream>>>(hbuf16, csr32, el2w, el2b, rowptr, aggout);
    mlp2<<<512, 256, 0, stream>>>(aggout, w2a_t, b2a, w2b_t, b2b, batch, sums);
    finalize<<<GG, 128, 0, stream>>>(sums, batch, (float*)d_out);
}

// Round 7
// 773.896 us; speedup vs baseline: 1.0225x; 1.0225x over previous
//
#include <hip/hip_runtime.h>
#include <hip/hip_bf16.h>

#define NN 500000
#define EE 2000000
#define GG 16384
#define ND 44
#define ED 12
#define HH 64
#define EMB 128
#define NBLK 123          // ceil(NN / 4096) scan blocks
#define NTILE (NN / 16)   // 31250, exact

typedef __attribute__((ext_vector_type(8))) short bf16x8;
typedef __attribute__((ext_vector_type(4))) float f32x4;
typedef __attribute__((ext_vector_type(8))) unsigned short u16x8;
typedef __attribute__((ext_vector_type(2))) _Float16 h2v;

// fp32 -> bf16 round-to-nearest-even, bit pattern as short
__device__ inline short f2bf(float v) {
    unsigned int x = __builtin_bit_cast(unsigned int, v);
    x += 0x7FFFu + ((x >> 16) & 1u);
    return (short)(x >> 16);
}
// fp32 <-> fp16 (RNE)
__device__ inline unsigned short f2h(float v) {
    return __builtin_bit_cast(unsigned short, (_Float16)v);
}
__device__ inline float h2f(unsigned short s) {
    return (float)__builtin_bit_cast(_Float16, s);
}
__device__ inline unsigned pkh(float a, float b) {
    return (unsigned)f2h(a) | ((unsigned)f2h(b) << 16);
}
__device__ inline float2 upk(unsigned u) {
    return make_float2((float)__builtin_bit_cast(_Float16, (unsigned short)(u & 0xffffu)),
                       (float)__builtin_bit_cast(_Float16, (unsigned short)(u >> 16)));
}
// f32 += dot(half2, half2) — single v_dot2_f32_f16 where available
__device__ inline float hdot2(unsigned a, unsigned b, float c) {
#if __has_builtin(__builtin_amdgcn_fdot2)
    return __builtin_amdgcn_fdot2(__builtin_bit_cast(h2v, a),
                                  __builtin_bit_cast(h2v, b), c, false);
#else
    float2 av = upk(a), bv = upk(b);
    return fmaf(av.y, bv.y, fmaf(av.x, bv.x, c));
#endif
}

// Wave-local LDS ordering fence (per-wave LDS buffers; does NOT drain vmcnt).
__device__ inline void wave_lds_fence() {
    asm volatile("s_waitcnt lgkmcnt(0)" ::: "memory");
    __builtin_amdgcn_sched_barrier(0);
}

// ---------------------------------------------------------------------------
// Weight prep: transpose to [n][k] layout, cast to bf16, zero-pad K of w1a to 64
__global__ __launch_bounds__(256) void prep_weights(
    const float* __restrict__ w1a, const float* __restrict__ w1b,
    const float* __restrict__ w2a, const float* __restrict__ w2b,
    short* __restrict__ o) {
    int t = blockIdx.x * 256 + threadIdx.x;
    if (t < 4096) {
        int n = t >> 6, k = t & 63;
        o[t] = f2bf(k < ND ? w1a[k * HH + n] : 0.f);
    } else if (t < 8192) {
        int u = t - 4096; int n = u >> 6, k = u & 63;
        o[t] = f2bf(w1b[k * HH + n]);
    } else if (t < 16384) {
        int u = t - 8192; int n = u >> 6, k = u & 63;
        o[t] = f2bf(w2a[k * EMB + n]);
    } else if (t < 32768) {
        int u = t - 16384; int n = u >> 7, k = u & 127;
        o[t] = f2bf(w2b[k * EMB + n]);
    }
}

// x [N][44] f32 -> xh [N][64] fp16, zero-padded, 128B-aligned rows.
// Vectorized: 8 outputs/thread, float4 reads, single 16B store.
__global__ __launch_bounds__(256) void x_to_h(const float* __restrict__ x,
                                             unsigned short* __restrict__ xh) {
    int t = blockIdx.x * 256 + threadIdx.x;      // one item per thread, grid exact
    int i = t >> 3, g = t & 7;
    int c0 = g * 8;
    u16x8 o = {0, 0, 0, 0, 0, 0, 0, 0};
    if (c0 < ND) {
        const float* rx = x + (size_t)i * ND + c0;
        if (c0 + 8 <= ND) {
            f32x4 v0 = *(const f32x4*)rx;
            f32x4 v1 = *(const f32x4*)(rx + 4);
#pragma unroll
            for (int j = 0; j < 4; ++j) { o[j] = f2h(v0[j]); o[j + 4] = f2h(v1[j]); }
        } else {                                   // c0 == 40: 4 valid + 4 pad
            f32x4 v0 = *(const f32x4*)rx;
#pragma unroll
            for (int j = 0; j < 4; ++j) o[j] = f2h(v0[j]);
        }
    }
    *(u16x8*)(xh + (size_t)i * 64 + c0) = o;
}

// ---------------------------------------------------------------------------
// CSR build: histogram of dst, exclusive scan, scatter by dst.
__global__ __launch_bounds__(256) void hist_kernel(const int* __restrict__ ei,
                                                   int* __restrict__ deg) {
    int e = blockIdx.x * 256 + threadIdx.x;
    if (e < EE) atomicAdd(&deg[ei[EE + e]], 1);
}

__global__ __launch_bounds__(256) void scan_reduce(const int* __restrict__ deg,
                                                   int* __restrict__ bsum) {
    int b = blockIdx.x, t = threadIdx.x;
    int base = b * 4096;
    int s = 0;
    for (int i = t; i < 4096; i += 256) {
        int g = base + i;
        if (g < NN) s += deg[g];
    }
#pragma unroll
    for (int off = 32; off; off >>= 1) s += __shfl_xor(s, off);
    __shared__ int ws[4];
    if ((t & 63) == 0) ws[t >> 6] = s;
    __syncthreads();
    if (t == 0) bsum[b] = ws[0] + ws[1] + ws[2] + ws[3];
}

__global__ __launch_bounds__(128) void scan_mid(const int* __restrict__ bsum,
                                                int* __restrict__ boff,
                                                int* __restrict__ rowptr) {
    int t = threadIdx.x;
    int v = (t < NBLK) ? bsum[t] : 0;
    int x = v;
#pragma unroll
    for (int off = 1; off < 64; off <<= 1) {
        int y = __shfl_up(x, off);
        if ((t & 63) >= off) x += y;
    }
    __shared__ int wt[2];
    if ((t & 63) == 63) wt[t >> 6] = x;
    __syncthreads();
    int xx = x + ((t >= 64) ? wt[0] : 0);
    if (t < NBLK) boff[t] = xx - v;
    if (t == 127) rowptr[NN] = xx;
}

__global__ __launch_bounds__(256) void scan_final(const int* __restrict__ deg,
                                                  const int* __restrict__ boff,
                                                  int* __restrict__ rowptr,
                                                  int* __restrict__ cursor) {
    int b = blockIdx.x, t = threadIdx.x;
    int base = b * 4096 + t * 16;
    int loc[16];
    int s = 0;
#pragma unroll
    for (int j = 0; j < 16; ++j) {
        int g = base + j;
        loc[j] = (g < NN) ? deg[g] : 0;
        s += loc[j];
    }
    int xinc = s;
#pragma unroll
    for (int off = 1; off < 64; off <<= 1) {
        int y = __shfl_up(xinc, off);
        if ((t & 63) >= off) xinc += y;
    }
    __shared__ int wt[4];
    if ((t & 63) == 63) wt[t >> 6] = xinc;
    __syncthreads();
    int wv = t >> 6, woff = 0;
#pragma unroll
    for (int k = 0; k < 4; ++k)
        if (k < wv) woff += wt[k];
    int run = boff[b] + woff + (xinc - s);
#pragma unroll
    for (int j = 0; j < 16; ++j) {
        int g = base + j;
        if (g < NN) { rowptr[g] = run; cursor[g] = run; }
        run += loc[j];
    }
}

// Scatter: build 32B CSR rows: [12 x fp16 edge-attr (24B) | src int (4B) | pad].
__global__ __launch_bounds__(256) void scatter_kernel(const int* __restrict__ ei,
                                                      const float* __restrict__ ea,
                                                      int* __restrict__ cursor,
                                                      unsigned int* __restrict__ csr) {
    int e = blockIdx.x * 256 + threadIdx.x;
    if (e < EE) {
        int dst = ei[EE + e];
        const float4* s = (const float4*)(ea + (size_t)e * ED);
        float4 a0 = s[0], a1 = s[1], a2 = s[2];
        uint4 P0, P1;
        P0.x = pkh(a0.x, a0.y); P0.y = pkh(a0.z, a0.w);
        P0.z = pkh(a1.x, a1.y); P0.w = pkh(a1.z, a1.w);
        P1.x = pkh(a2.x, a2.y); P1.y = pkh(a2.z, a2.w);
        P1.z = (unsigned)ei[e];   // src at word 6
        P1.w = 0u;
        int pos = atomicAdd(&cursor[dst], 1);
        uint4* d = (uint4*)(csr + (size_t)pos * 8);
        d[0] = P0; d[1] = P1;
    }
}

// ---------------------------------------------------------------------------
// Gather aggregation, 8 nodes/wave, fused skip-add + bf16 output:
//   out16[i][0:64] = bf16( xf[i] + sum_{e: dst=i} relu(xf[src] + ea@W + b) )
// Round-7 dataflow: chunks of <=64 edges. Each lane coalesced-loads ITS OWN
// edge's 32B CSR row once per chunk (2 dwordx4 / 64 edges); per-edge attrs
// come from 6 wave-uniform v_readlane feeding v_dot2_f32_f16 (SGPR src0).
// The only per-edge VMEM is the xh[src] gather -> 8-deep pipeline slots are
// 1 register each (sched_barrier keeps 8 gathers in flight).
template <int D>
__global__ __launch_bounds__(256) void agg_gather(
    const unsigned short* __restrict__ xh,
    const unsigned int* __restrict__ cea,
    const float* __restrict__ ew, const float* __restrict__ eb,
    const int* __restrict__ rowptr,
    short* __restrict__ out) {
    int lane = threadIdx.x & 63;
    int wv = threadIdx.x >> 6;
    int i0 = (blockIdx.x * 4 + wv) * 8;
    if (i0 >= NN) return;
    // weights packed as 6 fp16 pairs per lane (lanes >= D get zeros)
    unsigned wp0, wp1, wp2, wp3, wp4, wp5;
    float breg;
    if (D == 64 || lane < D) {
        wp0 = pkh(ew[0 * D + lane], ew[1 * D + lane]);
        wp1 = pkh(ew[2 * D + lane], ew[3 * D + lane]);
        wp2 = pkh(ew[4 * D + lane], ew[5 * D + lane]);
        wp3 = pkh(ew[6 * D + lane], ew[7 * D + lane]);
        wp4 = pkh(ew[8 * D + lane], ew[9 * D + lane]);
        wp5 = pkh(ew[10 * D + lane], ew[11 * D + lane]);
        breg = eb[lane];
    } else {
        wp0 = wp1 = wp2 = wp3 = wp4 = wp5 = 0u; breg = 0.f;
    }
    int rp = (lane <= 8) ? rowptr[i0 + lane] : 0;
    int beg = __builtin_amdgcn_readfirstlane(__builtin_amdgcn_readlane(rp, 0));
    int end = __builtin_amdgcn_readfirstlane(__builtin_amdgcn_readlane(rp, 8));

    auto SKIPLD = [&](int j) -> float {
        return h2f(xh[(size_t)(i0 + j) * 64 + lane]);
    };

    float acc = 0.f;
    int np = 0;
    int nb = __builtin_amdgcn_readlane(rp, 1);
    float sk = SKIPLD(0);
    // flush leading empty nodes (boundary == beg)
    while (np < 8 && nb == beg) {
        out[(size_t)(i0 + np) * 64 + lane] = f2bf(sk);   // acc == 0
        ++np;
        nb = (np < 8) ? __builtin_amdgcn_readlane(rp, np + 1) : 0x7fffffff;
        sk = (np < 8) ? SKIPLD(np) : 0.f;
    }

    if (beg >= end) return;   // all 8 nodes empty (already flushed above)

    int c0 = beg;
    while (c0 < end) {
        int cend = (end < c0 + 64) ? end : c0 + 64;
        // per-lane chunk row preload (coalesced 2x dwordx4 per lane)
        unsigned qa0 = 0, qa1 = 0, qa2 = 0, qa3 = 0, qa4 = 0, qa5 = 0;
        int qsrc = 0;
        if (c0 + lane < end) {
            const uint4* rp4 = (const uint4*)(cea + (size_t)(c0 + lane) * 8);
            uint4 a = rp4[0], b = rp4[1];
            qa0 = a.x; qa1 = a.y; qa2 = a.z; qa3 = a.w; qa4 = b.x; qa5 = b.y;
            qsrc = (int)b.z;
        }

        // pipeline slot = just the gathered source value (1 reg)
        auto LOADE = [&](int pos, unsigned short& XR) {
            int p = pos < cend ? pos : cend - 1;
            int off = p - c0;                                   // wave-uniform
            int src = __builtin_amdgcn_readlane(qsrc, off);
            XR = xh[(size_t)src * 64 + lane];
        };
        auto CONSUME = [&](int pos, unsigned short XR) {
            if (pos < cend) {
                int off = pos - c0;                             // wave-uniform
                unsigned a0 = __builtin_amdgcn_readlane(qa0, off);
                unsigned a1 = __builtin_amdgcn_readlane(qa1, off);
                unsigned a2 = __builtin_amdgcn_readlane(qa2, off);
                unsigned a3 = __builtin_amdgcn_readlane(qa3, off);
                unsigned a4 = __builtin_amdgcn_readlane(qa4, off);
                unsigned a5 = __builtin_amdgcn_readlane(qa5, off);
                float elin = breg;
                elin = hdot2(a0, wp0, elin);
                elin = hdot2(a1, wp1, elin);
                elin = hdot2(a2, wp2, elin);
                elin = hdot2(a3, wp3, elin);
                elin = hdot2(a4, wp4, elin);
                elin = hdot2(a5, wp5, elin);
                acc += fmaxf(h2f(XR) + elin, 0.f);
                int p1 = pos + 1;
                if (p1 == nb) {
                    do {
                        out[(size_t)(i0 + np) * 64 + lane] = f2bf(acc + sk);
                        acc = 0.f; ++np;
                        nb = (np < 8) ? __builtin_amdgcn_readlane(rp, np + 1) : 0x7fffffff;
                        sk = (np < 8) ? SKIPLD(np) : 0.f;
                    } while (p1 == nb);
                }
            }
        };

        unsigned short XA, XB, XC, XD, XE, XF, XG, XH;
        LOADE(c0 + 0, XA);
        LOADE(c0 + 1, XB);
        LOADE(c0 + 2, XC);
        LOADE(c0 + 3, XD);
        LOADE(c0 + 4, XE);
        LOADE(c0 + 5, XF);
        LOADE(c0 + 6, XG);
        LOADE(c0 + 7, XH);
        __builtin_amdgcn_sched_barrier(0);
        int base = c0;
        while (base < cend) {
            CONSUME(base + 0, XA);
            CONSUME(base + 1, XB);
            LOADE(base + 8, XA);
            LOADE(base + 9, XB);
            __builtin_amdgcn_sched_barrier(0);
            if (base + 2 >= cend) break;
            CONSUME(base + 2, XC);
            CONSUME(base + 3, XD);
            LOADE(base + 10, XC);
            LOADE(base + 11, XD);
            __builtin_amdgcn_sched_barrier(0);
            if (base + 4 >= cend) break;
            CONSUME(base + 4, XE);
            CONSUME(base + 5, XF);
            LOADE(base + 12, XE);
            LOADE(base + 13, XF);
            __builtin_amdgcn_sched_barrier(0);
            if (base + 6 >= cend) break;
            CONSUME(base + 6, XG);
            CONSUME(base + 7, XH);
            LOADE(base + 14, XG);
            LOADE(base + 15, XH);
            __builtin_amdgcn_sched_barrier(0);
            base += 8;
        }
        c0 = cend;
    }
}

// ---------------------------------------------------------------------------
// Node MLP 1: h = relu( relu(a @ w1a + b1a) @ w1b + b1b ), a = bf16[N][64] in.
// Persistent waves, register-resident weights (64 VGPR total), per-wave LDS.
#define HSTR1 68
__global__ __launch_bounds__(256, 3) void mlp1(
    const short* __restrict__ ain,
    const short* __restrict__ w1a_t, const float* __restrict__ b1a,
    const short* __restrict__ w1b_t, const float* __restrict__ b1b,
    unsigned short* __restrict__ h) {
    __shared__ float hid[4][16 * HSTR1];
    int lane = threadIdx.x & 63;
    int wv = threadIdx.x >> 6;
    int mrow = lane & 15, q = lane >> 4;
    float* hw = hid[wv];

    bf16x8 wa[4][2], wb[4][2];
    float ba[4], bb[4];
#pragma unroll
    for (int nt = 0; nt < 4; ++nt) {
        int n = nt * 16 + mrow;
        ba[nt] = b1a[n]; bb[nt] = b1b[n];
#pragma unroll
        for (int s = 0; s < 2; ++s) {
            wa[nt][s] = *(const bf16x8*)(w1a_t + n * 64 + s * 32 + q * 8);
            wb[nt][s] = *(const bf16x8*)(w1b_t + n * 64 + s * 32 + q * 8);
        }
    }

    int tile = blockIdx.x * 4 + wv;
    int stride = gridDim.x * 4;
    if (tile >= NTILE) return;
    bf16x8 a0 = *(const bf16x8*)(ain + (size_t)(tile * 16 + mrow) * 64 + q * 8);
    bf16x8 a1 = *(const bf16x8*)(ain + (size_t)(tile * 16 + mrow) * 64 + 32 + q * 8);
    while (true) {
        int nxt = tile + stride;
        bool more = nxt < NTILE;
        bf16x8 na0{}, na1{};
        if (more) {
            na0 = *(const bf16x8*)(ain + (size_t)(nxt * 16 + mrow) * 64 + q * 8);
            na1 = *(const bf16x8*)(ain + (size_t)(nxt * 16 + mrow) * 64 + 32 + q * 8);
        }
        int node0 = tile * 16;
#pragma unroll
        for (int nt = 0; nt < 4; ++nt) {
            f32x4 acc = {ba[nt], ba[nt], ba[nt], ba[nt]};
            acc = __builtin_amdgcn_mfma_f32_16x16x32_bf16(a0, wa[nt][0], acc, 0, 0, 0);
            acc = __builtin_amdgcn_mfma_f32_16x16x32_bf16(a1, wa[nt][1], acc, 0, 0, 0);
            int n = nt * 16 + mrow;
#pragma unroll
            for (int r = 0; r < 4; ++r)
                hw[(q * 4 + r) * HSTR1 + n] = fmaxf(acc[r], 0.f);
        }
        wave_lds_fence();
        bf16x8 af2[2];
#pragma unroll
        for (int s = 0; s < 2; ++s) {
            f32x4 v0 = *(const f32x4*)(hw + mrow * HSTR1 + s * 32 + q * 8);
            f32x4 v1 = *(const f32x4*)(hw + mrow * HSTR1 + s * 32 + q * 8 + 4);
#pragma unroll
            for (int j = 0; j < 4; ++j) { af2[s][j] = f2bf(v0[j]); af2[s][j + 4] = f2bf(v1[j]); }
        }
#pragma unroll
        for (int nt = 0; nt < 4; ++nt) {
            f32x4 acc = {bb[nt], bb[nt], bb[nt], bb[nt]};
            acc = __builtin_amdgcn_mfma_f32_16x16x32_bf16(af2[0], wb[nt][0], acc, 0, 0, 0);
            acc = __builtin_amdgcn_mfma_f32_16x16x32_bf16(af2[1], wb[nt][1], acc, 0, 0, 0);
            int n = nt * 16 + mrow;
#pragma unroll
            for (int r = 0; r < 4; ++r)
                h[(size_t)(node0 + q * 4 + r) * HH + n] = f2h(fmaxf(acc[r], 0.f));
        }
        if (!more) break;
        tile = nxt; a0 = na0; a1 = na1;
        wave_lds_fence();   // order this iter's hw reads vs next iter's writes
    }
}

// ---------------------------------------------------------------------------
// Node MLP 2 + fused mean-pool accumulate: input = bf16[N][64] (h+agg2 fused).
// Persistent waves (grid 512 = 2 blocks/CU). wa register-resident; w2b staged
// once per block into LDS (stride 136 shorts -> ~2-way bank alias, free).
#define HSTR2 132
#define WLSTR 136
__global__ __launch_bounds__(256, 2) void mlp2(
    const short* __restrict__ ain,
    const short* __restrict__ w2a_t, const float* __restrict__ b2a,
    const short* __restrict__ w2b_t, const float* __restrict__ b2b,
    const int* __restrict__ batch, float* __restrict__ sums) {
    __shared__ float buf[4][16 * HSTR2];
    __shared__ short wlds[EMB * WLSTR];
    int lane = threadIdx.x & 63;
    int wv = threadIdx.x >> 6;
    int mrow = lane & 15, q = lane >> 4;
    float* bw = buf[wv];

    // stage w2b -> LDS once per block (16384 shorts)
    for (int idx = threadIdx.x * 8; idx < EMB * EMB; idx += 2048) {
        int n = idx >> 7, k = idx & 127;
        *(bf16x8*)(wlds + n * WLSTR + k) = *(const bf16x8*)(w2b_t + idx);
    }

    bf16x8 wa[8][2];
    float ba[8], bb[8];
#pragma unroll
    for (int nt = 0; nt < 8; ++nt) {
        int n = nt * 16 + mrow;
        ba[nt] = b2a[n]; bb[nt] = b2b[n];
#pragma unroll
        for (int s = 0; s < 2; ++s)
            wa[nt][s] = *(const bf16x8*)(w2a_t + n * HH + s * 32 + q * 8);
    }
    __syncthreads();   // once: wlds visible to all waves

    int tile = blockIdx.x * 4 + wv;
    int stride = gridDim.x * 4;
    if (tile >= NTILE) return;
    bf16x8 a0 = *(const bf16x8*)(ain + (size_t)(tile * 16 + mrow) * 64 + q * 8);
    bf16x8 a1 = *(const bf16x8*)(ain + (size_t)(tile * 16 + mrow) * 64 + 32 + q * 8);
    int bv = (lane < 16) ? batch[tile * 16 + lane] : 0;
    while (true) {
        int nxt = tile + stride;
        bool more = nxt < NTILE;
        bf16x8 na0{}, na1{};
        int nbv = 0;
        if (more) {
            na0 = *(const bf16x8*)(ain + (size_t)(nxt * 16 + mrow) * 64 + q * 8);
            na1 = *(const bf16x8*)(ain + (size_t)(nxt * 16 + mrow) * 64 + 32 + q * 8);
            nbv = (lane < 16) ? batch[nxt * 16 + lane] : 0;
        }
        // GEMM1: 64 -> 128, relu, to LDS (transpose staging)
#pragma unroll
        for (int nt = 0; nt < 8; ++nt) {
            f32x4 acc = {ba[nt], ba[nt], ba[nt], ba[nt]};
            acc = __builtin_amdgcn_mfma_f32_16x16x32_bf16(a0, wa[nt][0], acc, 0, 0, 0);
            acc = __builtin_amdgcn_mfma_f32_16x16x32_bf16(a1, wa[nt][1], acc, 0, 0, 0);
            int n = nt * 16 + mrow;
#pragma unroll
            for (int r = 0; r < 4; ++r)
                bw[(q * 4 + r) * HSTR2 + n] = fmaxf(acc[r], 0.f);
        }
        wave_lds_fence();
        bf16x8 af2[4];
#pragma unroll
        for (int s = 0; s < 4; ++s) {
            f32x4 v0 = *(const f32x4*)(bw + mrow * HSTR2 + s * 32 + q * 8);
            f32x4 v1 = *(const f32x4*)(bw + mrow * HSTR2 + s * 32 + q * 8 + 4);
#pragma unroll
            for (int j = 0; j < 4; ++j) { af2[s][j] = f2bf(v0[j]); af2[s][j + 4] = f2bf(v1[j]); }
        }
        // GEMM2: 128 -> 128, B-fragments streamed from LDS, raw acc to LDS
#pragma unroll
        for (int nt = 0; nt < 8; ++nt) {
            f32x4 acc = {bb[nt], bb[nt], bb[nt], bb[nt]};
#pragma unroll
            for (int s = 0; s < 4; ++s) {
                bf16x8 bfrag = *(const bf16x8*)(wlds + (nt * 16 + mrow) * WLSTR + s * 32 + q * 8);
                acc = __builtin_amdgcn_mfma_f32_16x16x32_bf16(af2[s], bfrag, acc, 0, 0, 0);
            }
#pragma unroll
            for (int r = 0; r < 4; ++r)
                bw[(q * 4 + r) * HSTR2 + nt * 16 + mrow] = acc[r];
        }
        wave_lds_fence();
        // fused mean-pool accumulate (batch sorted -> few runs per tile)
#pragma unroll
        for (int cp = 0; cp < 2; ++cp) {
            int col = lane + cp * 64;
            float run = 0.f;
            int bprev = __shfl(bv, 0);
            for (int i = 0; i < 16; ++i) {
                int bg = __shfl(bv, i);
                if (bg != bprev) {
                    atomicAdd(&sums[bprev * EMB + col], run);
                    run = 0.f; bprev = bg;
                }
                run += bw[i * HSTR2 + col];
            }
            atomicAdd(&sums[bprev * EMB + col], run);
        }
        if (!more) break;
        tile = nxt; a0 = na0; a1 = na1; bv = nbv;
        wave_lds_fence();   // order pooling reads vs next iter's GEMM1 writes
    }
}

// ---------------------------------------------------------------------------
__global__ __launch_bounds__(128) void finalize(
    const float* __restrict__ sums, const int* __restrict__ batch,
    float* __restrict__ out) {
    int g = blockIdx.x;
    __shared__ int cnt_s;
    if (threadIdx.x == 0) {
        int lo = 0, hi = NN;
        while (lo < hi) { int mid = (lo + hi) >> 1; if (batch[mid] < g) lo = mid + 1; else hi = mid; }
        int lo2 = lo, hi2 = NN;
        while (lo2 < hi2) { int mid = (lo2 + hi2) >> 1; if (batch[mid] < g + 1) lo2 = mid + 1; else hi2 = mid; }
        cnt_s = lo2 - lo;
    }
    __syncthreads();
    int c = cnt_s > 1 ? cnt_s : 1;
    out[g * EMB + threadIdx.x] = sums[g * EMB + threadIdx.x] / (float)c;
}

// ---------------------------------------------------------------------------
extern "C" void kernel_launch(void* const* d_in, const int* in_sizes, int n_in,
                              void* d_out, int out_size, void* d_ws, size_t ws_size,
                              hipStream_t stream) {
    const float* x    = (const float*)d_in[0];
    const float* ea   = (const float*)d_in[1];
    const int*   ei   = (const int*)d_in[2];
    const int*   batch= (const int*)d_in[3];
    const float* el1w = (const float*)d_in[4];
    const float* el1b = (const float*)d_in[5];
    const float* w1a  = (const float*)d_in[6];
    const float* b1a  = (const float*)d_in[7];
    const float* w1b  = (const float*)d_in[8];
    const float* b1b  = (const float*)d_in[9];
    const float* el2w = (const float*)d_in[10];
    const float* el2b = (const float*)d_in[11];
    const float* w2a  = (const float*)d_in[12];
    const float* b2a  = (const float*)d_in[13];
    const float* w2b  = (const float*)d_in[14];
    const float* b2b  = (const float*)d_in[15];

    char* ws = (char*)d_ws;
    short*          aggout = (short*)ws;                    // [N][64] bf16 (64,000,000 B), both layers
    unsigned short* hbuf16 = (unsigned short*)(ws + 64000000); // [N][64] fp16 (64,000,000 B)
    unsigned int*   csr32  = (unsigned int*)(ws + 128000000);  // [E] 32B rows (64,000,000 B)
    int*   rowptr = (int*)(ws + 192000000);                 // N+1
    int*   cursor = (int*)(ws + 194000064);                 // N
    int*   deg    = (int*)(ws + 196000064);                 // N
    int*   bsum   = (int*)(ws + 198000064);                 // NBLK
    int*   boff   = (int*)(ws + 198000576);                 // NBLK
    float* sums   = (float*)(ws + 198001088);               // G*128 f32
    short* wts    = (short*)(ws + 206389696);               // 32768 shorts
    unsigned short* xh = (unsigned short*)(ws + 208000000); // [N][64] fp16 (64,000,000 B)
    short* w1a_t = wts;
    short* w1b_t = wts + 4096;
    short* w2a_t = wts + 8192;
    short* w2b_t = wts + 16384;

    hipMemsetAsync(deg, 0, (size_t)NN * 4, stream);
    hipMemsetAsync(sums, 0, (size_t)GG * EMB * 4, stream);

    prep_weights<<<128, 256, 0, stream>>>(w1a, w1b, w2a, w2b, wts);
    x_to_h<<<15625, 256, 0, stream>>>(x, xh);   // NN*8 / 256 exact
    // CSR build (+ fp16 attr pack + src fused into 32B rows)
    hist_kernel<<<(EE + 255) / 256, 256, 0, stream>>>(ei, deg);
    scan_reduce<<<NBLK, 256, 0, stream>>>(deg, bsum);
    scan_mid<<<1, 128, 0, stream>>>(bsum, boff, rowptr);
    scan_final<<<NBLK, 256, 0, stream>>>(deg, boff, rowptr, cursor);
    scatter_kernel<<<(EE + 255) / 256, 256, 0, stream>>>(ei, ea, cursor, csr32);
    // Layer 1
    agg_gather<ND><<<NN / 32, 256, 0, stream>>>(xh, csr32, el1w, el1b, rowptr, aggout);
    mlp1<<<1024, 256, 0, stream>>>(aggout, w1a_t, b1a, w1b_t, b1b, hbuf16);
    // Layer 2
    agg_gather<HH><<<NN / 32, 256, 0, stream>>>(hbuf16, csr32, el2w, el2b, rowptr, aggout);
    mlp2<<<512, 256, 0, stream>>>(aggout, w2a_t, b2a, w2b_t, b2b, batch, sums);
    finalize<<<GG, 128, 0, stream>>>(sums, batch, (float*)d_out);
}